// Round 7
// baseline (310.410 us; speedup 1.0000x reference)
//
#include <hip/hip_runtime.h>
#include <hip/hip_bf16.h>
#include <stdint.h>

#define NN 32
#define CC 64
#define TTOT 256
#define VV 25
#define NS 3
constexpr int TV  = TTOT * VV;            // 6400
constexpr int CTV = CC * TV;              // 409600
constexpr size_t PLANE = (size_t)NN * CTV; // 13107200

typedef unsigned short ushort_t;
using short8 = __attribute__((ext_vector_type(8))) short;
using f32x4  = __attribute__((ext_vector_type(4))) float;

static __device__ __forceinline__ ushort_t f2bf(float f) {
  __hip_bfloat16 h = __float2bfloat16(f);   // RNE, compiles to v_cvt
  return reinterpret_cast<ushort_t&>(h);
}
static __device__ __forceinline__ float bf2f(ushort_t h) {
  union { uint32_t u; float f; } v; v.u = ((uint32_t)h) << 16;
  return v.f;
}
// element offset into a [row][128] bf16 tile, XOR-swizzled (byte ^= (row&7)<<4)
static __device__ __forceinline__ int SWZ(int row, int k) {
  return ((row << 7) + k) ^ ((row & 7) << 3);
}
static __device__ __forceinline__ f32x4 mfma16(short8 a, short8 b, f32x4 c) {
  return __builtin_amdgcn_mfma_f32_16x16x32_bf16(a, b, c, 0, 0, 0);
}
static __device__ __forceinline__ short8 negbf8(short8 x) {
  short8 r;
#pragma unroll
  for (int j = 0; j < 8; ++j) r[j] = x[j] ^ (short)0x8000;
  return r;
}

// ---------------------------------------------------------------------------
// K0: pre-fragment Wd (k'=2c+comp interleaved) and Wa/Wb (k=c planar) to bf16
// wfrag[i][ot(8)][m(4)][lane(64)][j(8)];  wab[i][mt(4)][ks(4)][lane(64)][j(8)]
// ---------------------------------------------------------------------------
__global__ __launch_bounds__(256) void k0_wfrag(
    const float* __restrict__ Wd, const float* __restrict__ Wa,
    const float* __restrict__ Wb, ushort_t* __restrict__ wfrag,
    ushort_t* __restrict__ wab)
{
  const int i = blockIdx.x;
  for (int e = threadIdx.x; e < 16384; e += 256) {
    int ot = e >> 11, m = (e >> 9) & 3, l = (e >> 3) & 63, j = e & 7;
    int r  = ot * 16 + (l & 15);
    // k-map: within m-step, k-row = gw*8 + j  <->  c = m*16 + gw*4 + (j>>1), comp = j&1
    int c = m * 16 + ((l >> 4) << 2) + (j >> 1), comp = j & 1;
    wfrag[(size_t)i * 16384 + e] = f2bf(Wd[(size_t)i * 16384 + r * 128 + comp * 64 + c]);
  }
  for (int e = threadIdx.x; e < 8192; e += 256) {
    int mt = e >> 11, ks = (e >> 9) & 3, l = (e >> 3) & 63, j = e & 7;
    int r  = mt * 16 + (l & 15);                 // 0..63: 0-31 Wa, 32-63 Wb
    int kp = ks * 32 + ((l >> 4) << 3) + j;      // channel 0..127
    float v = (r < 32) ? Wa[((size_t)i * 32 + r) * 128 + kp]
                       : Wb[((size_t)i * 32 + (r - 32)) * 128 + kp];
    wab[(size_t)i * 8192 + e] = f2bf(v);
  }
}

// ---------------------------------------------------------------------------
// K1: per (n, tc) with 4 t's: conv (MFMA, weights from wab) -> Ga/Gb
//     (k-layout half + t*16 + it, b64 writes) -> Gram via MFMA.
// Spart[3][32][64][25][25][2]
// ---------------------------------------------------------------------------
__global__ __launch_bounds__(256) void k1_spart(
    const float* __restrict__ xr, const float* __restrict__ xi,
    const ushort_t* __restrict__ wab, const float* __restrict__ ba,
    const float* __restrict__ bb, float* __restrict__ Spart)
{
  const int tc = blockIdx.x, n = blockIdx.y;
  const int tid = threadIdx.x, lane = tid & 63, wv = tid >> 6;
  const int r16 = lane & 15, gw = lane >> 4;
  __shared__ alignas(16) ushort_t zc[128 * 128]; // [pos2=t*32+v][c] swizzled
  __shared__ alignas(16) ushort_t Ga[32 * 128];  // [u][k: half + t*16 + it] swz
  __shared__ alignas(16) ushort_t Gb[32 * 128];

  // stage zc: float4 loads (100 contiguous floats per c = 25 float4)
  for (int e4 = tid; e4 < 128 * 25; e4 += 256) {
    int c = e4 / 25, q = e4 % 25;
    const float* src = (c < 64) ? xr : xi;
    float4 w = *(const float4*)&src[(size_t)n * CTV + (c & 63) * TV + tc * 100 + q * 4];
#pragma unroll
    for (int jj = 0; jj < 4; ++jj) {
      int g = q * 4 + jj, t = g / 25, v = g - t * 25;
      zc[SWZ(t * 32 + v, c)] = f2bf(((const float*)&w)[jj]);
    }
  }
  // zero-pad v=25..31
  for (int e = tid; e < 28 * 128; e += 256) {
    int r7 = e >> 7, c = e & 127;
    int t = r7 / 7, vv = 25 + r7 % 7;
    zc[SWZ(t * 32 + vv, c)] = 0;
  }

  const int mu = wv >> 1, nv = wv & 1;

  for (int i = 0; i < NS; ++i) {
    __syncthreads(); // zc ready (i==0); WAR on Ga/Gb vs previous gram

    // conv: wave wv = component (0=ar 1=ai 2=br 3=bi)
    {
      short8 afr[4];
#pragma unroll
      for (int ks = 0; ks < 4; ++ks)
        afr[ks] = *(const short8*)&wab[((((size_t)i * 4 + wv) * 4 + ks) * 64 + lane) * 8];
      float bias[4];
#pragma unroll
      for (int j = 0; j < 4; ++j) {
        int row = wv * 16 + gw * 4 + j;
        bias[j] = (row < 32) ? ba[i * 32 + row] : bb[i * 32 + (row - 32)];
      }
      ushort_t* gbuf = (wv < 2) ? Ga : Gb;
      const int half = (wv & 1) * 64;
      for (int nt = 0; nt < 8; ++nt) {
        f32x4 acc = {0.f, 0.f, 0.f, 0.f};
        const int brow = nt * 16 + r16;
#pragma unroll
        for (int ks = 0; ks < 4; ++ks) {
          short8 bfr = *(const short8*)&zc[SWZ(brow, ks * 32 + gw * 8)];
          acc = mfma16(afr[ks], bfr, acc);
        }
        int pos2 = nt * 16 + r16;
        int t = pos2 >> 5, v = pos2 & 31;
        int k0w = half + t * 16 + gw * 4;     // it = gw*4+j contiguous
        uint32_t w0 = (uint32_t)f2bf(acc[0] + bias[0]) | ((uint32_t)f2bf(acc[1] + bias[1]) << 16);
        uint32_t w1 = (uint32_t)f2bf(acc[2] + bias[2]) | ((uint32_t)f2bf(acc[3] + bias[3]) << 16);
        uint2 pk; pk.x = w0; pk.y = w1;
        *(uint2*)&gbuf[SWZ(v, k0w)] = pk;
      }
    }
    __syncthreads();

    // Gram via MFMA: wave (mu,nv) computes S[mu*16..+16)[nv*16..+16)
    {
      const int urow = mu * 16 + r16;
      const int vrow = nv * 16 + r16;
      f32x4 Prr = {0.f,0.f,0.f,0.f}, Pii = {0.f,0.f,0.f,0.f};
      f32x4 Pri = {0.f,0.f,0.f,0.f}, Pir = {0.f,0.f,0.f,0.f};
#pragma unroll
      for (int ks = 0; ks < 2; ++ks) {
        int ko = ks * 32 + gw * 8;
        short8 arF = *(const short8*)&Ga[SWZ(urow, ko)];
        short8 aiF = *(const short8*)&Ga[SWZ(urow, 64 + ko)];
        short8 brF = *(const short8*)&Gb[SWZ(vrow, ko)];
        short8 biF = *(const short8*)&Gb[SWZ(vrow, 64 + ko)];
        Prr = mfma16(arF, brF, Prr);
        Pii = mfma16(aiF, biF, Pii);
        Pri = mfma16(arF, biF, Pri);
        Pir = mfma16(aiF, brF, Pir);
      }
#pragma unroll
      for (int j = 0; j < 4; ++j) {
        int u = mu * 16 + gw * 4 + j;
        int v = nv * 16 + r16;
        if (u < VV && v < VV) {
          size_t idx = ((((size_t)i * NN + n) * 64 + tc) * 625 + u * 25 + v) * 2;
          Spart[idx]     = Prr[j] - Pii[j];
          Spart[idx + 1] = Pri[j] + Pir[j];
        }
      }
    }
  }
}

// ---------------------------------------------------------------------------
// K2: reduce Spart over tc, /4096, complex softmax over u, + (A+PA),
//     then emit packed bf16 hi/lo S-fragments in per-lane MFMA order.
// sfrag[i][n][m(4)][nt(2)][lane(64)][j(8)]  (m: Srh,Srl,Sih,Sil)
// ---------------------------------------------------------------------------
__global__ __launch_bounds__(256) void k2_softmax(
    const float* __restrict__ Spart, const float* __restrict__ Aw,
    const float* __restrict__ PA, ushort_t* __restrict__ sfrag)
{
  const int i = blockIdx.x, n = blockIdx.y, tid = threadIdx.x;
  __shared__ float ez[625 * 2];
  __shared__ float den[25 * 2];
  for (int e = tid; e < 625; e += 256) {
    float sr = 0.f, si = 0.f;
    const float* p = Spart + (((size_t)i * NN + n) * 64 * 625 + e) * 2;
    for (int tcb = 0; tcb < 64; ++tcb) { sr += p[0]; si += p[1]; p += 625 * 2; }
    sr *= (1.f / 4096.f); si *= (1.f / 4096.f);
    float m = expf(sr);
    ez[e * 2] = m * cosf(si);
    ez[e * 2 + 1] = m * sinf(si);
  }
  __syncthreads();
  if (tid < 25) {
    float dr = 0.f, di = 0.f;
    for (int u = 0; u < 25; ++u) { dr += ez[(u * 25 + tid) * 2]; di += ez[(u * 25 + tid) * 2 + 1]; }
    float inv = 1.f / (dr * dr + di * di);
    den[tid * 2] = dr * inv; den[tid * 2 + 1] = -di * inv; // conj(d)/|d|^2
  }
  __syncthreads();
  for (int e = tid; e < 625; e += 256) {
    int v = e % 25;
    float er = ez[e * 2], ei = ez[e * 2 + 1];
    float dr = den[v * 2], di = den[v * 2 + 1];
    float outr = er * dr - ei * di + Aw[i * 625 + e] + PA[i * 625 + e];
    float outi = er * di + ei * dr;
    ez[e * 2] = outr; ez[e * 2 + 1] = outi;   // finalize in place
  }
  __syncthreads();
  // pack fragments (m: 0=Srh 1=Srl 2=Sih 3=Sil)
  for (int e = tid; e < 512; e += 256) {
    int l = e & 63, nt = (e >> 6) & 1, m = e >> 7;
    int u0 = (l >> 4) << 3, v = nt * 16 + (l & 15);
    short8 pk;
#pragma unroll
    for (int j = 0; j < 8; ++j) {
      int u = u0 + j;
      float val = 0.f;
      if (u < VV && v < VV) {
        float sr_ = ez[(u * 25 + v) * 2], si_ = ez[(u * 25 + v) * 2 + 1];
        float base = (m < 2) ? sr_ : si_;
        if (m & 1) { float hi = bf2f(f2bf(base)); val = base - hi; }
        else val = base;
      }
      pk[j] = (short)f2bf(val);
    }
    *(short8*)&sfrag[((size_t)(i * NN + n) * 512 + e) * 8] = pk;
  }
}

// ---------------------------------------------------------------------------
// K3: block = (tq, n): 4 waves, wave wv owns t = tq*4+wv END-TO-END.
// No z LDS round-trip: phase-A C-frags pack per-lane into phase-B B-frags
// (k-permutation baked into wfrag by k0). LDS: coalesced x-stage only.
// Two barriers total (x-stage, BN stats).
// ---------------------------------------------------------------------------
__global__ __launch_bounds__(256) void k3_y(
    const float* __restrict__ xr, const float* __restrict__ xi,
    const ushort_t* __restrict__ sfrag, const ushort_t* __restrict__ wfrag,
    const float* __restrict__ bd, float* __restrict__ out,
    float* __restrict__ bnpart)
{
  const int tq = blockIdx.x, n = blockIdx.y;
  const int tid = threadIdx.x, lane = tid & 63, wv = tid >> 6;
  const int r16 = lane & 15, gw = lane >> 4;
  __shared__ alignas(16) ushort_t xs[128 * 128]; // [c'][tl*32+u] swizzled
  __shared__ float stats[4][128][2];

  // cooperative x-stage: 128 c'-rows x 100 floats (4 t's), coalesced float4
  for (int e4 = tid; e4 < 128 * 25; e4 += 256) {
    int c = e4 / 25, q = e4 % 25;
    const float* src = (c < 64) ? xr : xi;
    float4 w = *(const float4*)&src[(size_t)n * CTV + (c & 63) * TV + tq * 100 + q * 4];
#pragma unroll
    for (int jj = 0; jj < 4; ++jj) {
      int g = q * 4 + jj, t = g / 25, u = g - t * 25;
      xs[SWZ(c, t * 32 + u)] = f2bf(((const float*)&w)[jj]);
    }
  }
  for (int e = tid; e < 128 * 28; e += 256) { // pad u=25..31
    int c = e / 28, r = e % 28;
    int t = r / 7, u = 25 + r % 7;
    xs[SWZ(c, t * 32 + u)] = 0;
  }
  __syncthreads();

  const int tl = wv;            // wave's local t
  const int kx = tl * 32 + gw * 8;

  f32x4 acc[8][2];
#pragma unroll
  for (int a = 0; a < 8; ++a) { acc[a][0] = {0.f,0.f,0.f,0.f}; acc[a][1] = {0.f,0.f,0.f,0.f}; }

#pragma unroll 1
  for (int i = 0; i < NS; ++i) {
    // S fragments: 8 coalesced 16B loads (L2-hot)
    const ushort_t* sb = sfrag + (size_t)(i * NN + n) * 4096;
    short8 sf[4][2];
#pragma unroll
    for (int m = 0; m < 4; ++m)
#pragma unroll
      for (int nt = 0; nt < 2; ++nt)
        sf[m][nt] = *(const short8*)&sb[((m * 2 + nt) * 64 + lane) * 8];
    short8 sn0[2], sn1[2];
#pragma unroll
    for (int nt = 0; nt < 2; ++nt) { sn0[nt] = negbf8(sf[2][nt]); sn1[nt] = negbf8(sf[3][nt]); }

    // phase A: z = X2*S per c-tile; pack C-frag -> B-frag in registers
    short8 bp[4][2];
#pragma unroll
    for (int tile = 0; tile < 4; ++tile) {
      short8 axr = *(const short8*)&xs[SWZ(tile * 16 + r16, kx)];
      short8 axi = *(const short8*)&xs[SWZ(64 + tile * 16 + r16, kx)];
#pragma unroll
      for (int nt = 0; nt < 2; ++nt) {
        f32x4 zr = {0.f,0.f,0.f,0.f}, zi = {0.f,0.f,0.f,0.f};
        zr = mfma16(axr, sf[0][nt], zr);
        zr = mfma16(axr, sf[1][nt], zr);
        zr = mfma16(axi, sn0[nt], zr);
        zr = mfma16(axi, sn1[nt], zr);
        zi = mfma16(axr, sf[2][nt], zi);
        zi = mfma16(axr, sf[3][nt], zi);
        zi = mfma16(axi, sf[0][nt], zi);
        zi = mfma16(axi, sf[1][nt], zi);
        short8 pk;
#pragma unroll
        for (int j = 0; j < 4; ++j) {
          pk[2 * j]     = (short)f2bf(zr[j]);
          pk[2 * j + 1] = (short)f2bf(zi[j]);
        }
        bp[tile][nt] = pk;
      }
    }

    // phase B: y += Wd[i] * z  (B-frags in registers; no barrier, no LDS)
    const ushort_t* wb = wfrag + (size_t)i * 16384;
#pragma unroll
    for (int ot = 0; ot < 8; ++ot) {
#pragma unroll
      for (int m = 0; m < 4; ++m) {
        short8 a = *(const short8*)&wb[(((ot * 4 + m) * 64) + lane) * 8];
        acc[ot][0] = mfma16(a, bp[m][0], acc[ot][0]);
        acc[ot][1] = mfma16(a, bp[m][1], acc[ot][1]);
      }
    }
  }

  // epilogue: bias, write y (t = tq*4+wv), BN partials
  const int t = tq * 4 + tl;
#pragma unroll
  for (int ot = 0; ot < 8; ++ot) {
#pragma unroll
    for (int j = 0; j < 4; ++j) {
      int row = ot * 16 + gw * 4 + j;
      float bias = bd[row] + bd[128 + row] + bd[256 + row];
      float s = 0.f, q = 0.f;
#pragma unroll
      for (int nt = 0; nt < 2; ++nt) {
        int v = nt * 16 + r16;
        float val = acc[ot][nt][j] + bias;
        if (v < VV) {
          out[(size_t)(row >> 6) * PLANE + (size_t)n * CTV + (row & 63) * TV + t * VV + v] = val;
          s += val; q += val * val;
        }
      }
#pragma unroll
      for (int d = 1; d < 16; d <<= 1) { s += __shfl_xor(s, d); q += __shfl_xor(q, d); }
      if (r16 == 0) { stats[wv][row][0] = s; stats[wv][row][1] = q; }
    }
  }
  __syncthreads();
  if (tid < 128) {
    float s = stats[0][tid][0] + stats[1][tid][0] + stats[2][tid][0] + stats[3][tid][0];
    float q = stats[0][tid][1] + stats[1][tid][1] + stats[2][tid][1] + stats[3][tid][1];
    size_t b = (size_t)n * 64 + tq;
    bnpart[(b * 128 + tid) * 2]     = s;
    bnpart[(b * 128 + tid) * 2 + 1] = q;
  }
}

// ---------------------------------------------------------------------------
// K4: reduce bnpart (2048 partials) -> per-channel coeff
// ---------------------------------------------------------------------------
__global__ __launch_bounds__(256) void k4_stats(
    const float* __restrict__ bnpart, const float* __restrict__ bnw,
    const float* __restrict__ bnb, float* __restrict__ coeff)
{
  const int o = blockIdx.x, tid = threadIdx.x;
  float sr = 0.f, qr = 0.f, si = 0.f, qi = 0.f;
  for (int b = tid; b < 2048; b += 256) {
    const float* p = bnpart + ((size_t)b * 128 + o) * 2;
    sr += p[0]; qr += p[1];
    const float* p2 = bnpart + ((size_t)b * 128 + 64 + o) * 2;
    si += p2[0]; qi += p2[1];
  }
#pragma unroll
  for (int d = 1; d < 64; d <<= 1) {
    sr += __shfl_xor(sr, d); qr += __shfl_xor(qr, d);
    si += __shfl_xor(si, d); qi += __shfl_xor(qi, d);
  }
  __shared__ float red[4][4];
  int lane = tid & 63, wv = tid >> 6;
  if (lane == 0) { red[wv][0] = sr; red[wv][1] = qr; red[wv][2] = si; red[wv][3] = qi; }
  __syncthreads();
  if (tid == 0) {
    sr = red[0][0] + red[1][0] + red[2][0] + red[3][0];
    qr = red[0][1] + red[1][1] + red[2][1] + red[3][1];
    si = red[0][2] + red[1][2] + red[2][2] + red[3][2];
    qi = red[0][3] + red[1][3] + red[2][3] + red[3][3];
    const float invM = 1.f / (float)((size_t)NN * TTOT * VV);
    float mur = sr * invM, mui = si * invM;
    float var = (qr + qi) * invM - mur * mur - mui * mui;
    float inv = rsqrtf(var + 1e-5f);
    coeff[o * 4 + 0] = mur; coeff[o * 4 + 1] = mui;
    coeff[o * 4 + 2] = inv * bnw[o]; coeff[o * 4 + 3] = bnb[o];
  }
}

// ---------------------------------------------------------------------------
// K5: yn = (y - mu)*scale + shift + x  (in-place on d_out, vectorized)
// ---------------------------------------------------------------------------
__global__ __launch_bounds__(256) void k5_norm(
    const float* __restrict__ xr, const float* __restrict__ xi,
    const float* __restrict__ coeff, float* __restrict__ out)
{
  size_t idx0 = ((size_t)blockIdx.x * 256 + threadIdx.x) * 4;
  size_t stride = (size_t)gridDim.x * 256 * 4;
  for (size_t e = idx0; e < PLANE; e += stride) {
    int o = (int)((e / TV) & 63);
    float4 cf = *(const float4*)&coeff[o * 4];
    float4 yr = *(float4*)&out[e];
    float4 yi = *(float4*)&out[PLANE + e];
    float4 vr = *(const float4*)&xr[e];
    float4 vi = *(const float4*)&xi[e];
    yr.x = (yr.x - cf.x) * cf.z + cf.w + vr.x;
    yr.y = (yr.y - cf.x) * cf.z + cf.w + vr.y;
    yr.z = (yr.z - cf.x) * cf.z + cf.w + vr.z;
    yr.w = (yr.w - cf.x) * cf.z + cf.w + vr.w;
    yi.x = (yi.x - cf.y) * cf.z + vi.x;
    yi.y = (yi.y - cf.y) * cf.z + vi.y;
    yi.z = (yi.z - cf.y) * cf.z + vi.z;
    yi.w = (yi.w - cf.y) * cf.z + vi.w;
    *(float4*)&out[e] = yr;
    *(float4*)&out[PLANE + e] = yi;
  }
}

// ---------------------------------------------------------------------------
extern "C" void kernel_launch(void* const* d_in, const int* in_sizes, int n_in,
                              void* d_out, int out_size, void* d_ws, size_t ws_size,
                              hipStream_t stream) {
  const float* xr  = (const float*)d_in[0];
  const float* xi  = (const float*)d_in[1];
  const float* Aw  = (const float*)d_in[2];
  const float* PA  = (const float*)d_in[3];
  const float* Wa  = (const float*)d_in[4];
  const float* ba  = (const float*)d_in[5];
  const float* Wb  = (const float*)d_in[6];
  const float* bb  = (const float*)d_in[7];
  const float* Wd  = (const float*)d_in[8];
  const float* bd  = (const float*)d_in[9];
  const float* bnw = (const float*)d_in[10];
  const float* bnb = (const float*)d_in[11];
  float* out = (float*)d_out;
  float* ws = (float*)d_ws;

  // ws layout (floats). bnpart aliases Spart (Spart dead after k2).
  float*    Spart  = ws;                         // 7,680,000 floats
  float*    bnpart = ws;                         // 524,288 floats (alias)
  ushort_t* sfrag  = (ushort_t*)(ws + 7680000);  // 3*32*512*8 = 393,216 ushorts
  ushort_t* wfrag  = (ushort_t*)(ws + 7876608);  // 49,152 ushorts
  ushort_t* wab    = (ushort_t*)(ws + 7901184);  // 24,576 ushorts
  float*    coeff  = ws + 7913472;               // 256 floats
  // total ≈ 31.7 MB

  k0_wfrag<<<NS, 256, 0, stream>>>(Wd, Wa, Wb, wfrag, wab);
  k1_spart<<<dim3(64, NN), 256, 0, stream>>>(xr, xi, wab, ba, bb, Spart);
  k2_softmax<<<dim3(NS, NN), 256, 0, stream>>>(Spart, Aw, PA, sfrag);
  k3_y<<<dim3(64, NN), 256, 0, stream>>>(xr, xi, sfrag, wfrag, bd, out, bnpart);
  k4_stats<<<64, 256, 0, stream>>>(bnpart, bnw, bnb, coeff);
  k5_norm<<<6400, 256, 0, stream>>>(xr, xi, coeff, out);
}

// Round 8
// 246.380 us; speedup vs baseline: 1.2599x; 1.2599x over previous
//
#include <hip/hip_runtime.h>
#include <hip/hip_bf16.h>
#include <stdint.h>

#define NN 32
#define CC 64
#define TTOT 256
#define VV 25
#define NS 3
constexpr int TV  = TTOT * VV;            // 6400
constexpr int CTV = CC * TV;              // 409600
constexpr size_t PLANE = (size_t)NN * CTV; // 13107200

typedef unsigned short ushort_t;
using short8 = __attribute__((ext_vector_type(8))) short;
using f32x4  = __attribute__((ext_vector_type(4))) float;

static __device__ __forceinline__ ushort_t f2bf(float f) {
  __hip_bfloat16 h = __float2bfloat16(f);   // RNE, compiles to v_cvt
  return reinterpret_cast<ushort_t&>(h);
}
static __device__ __forceinline__ float bf2f(ushort_t h) {
  union { uint32_t u; float f; } v; v.u = ((uint32_t)h) << 16;
  return v.f;
}
// element offset into a [row][128] bf16 tile, XOR-swizzled (byte ^= (row&7)<<4)
static __device__ __forceinline__ int SWZ(int row, int k) {
  return ((row << 7) + k) ^ ((row & 7) << 3);
}
static __device__ __forceinline__ f32x4 mfma16(short8 a, short8 b, f32x4 c) {
  return __builtin_amdgcn_mfma_f32_16x16x32_bf16(a, b, c, 0, 0, 0);
}
static __device__ __forceinline__ short8 negbf8(short8 x) {
  short8 r;
#pragma unroll
  for (int j = 0; j < 8; ++j) r[j] = x[j] ^ (short)0x8000;
  return r;
}

// ---------------------------------------------------------------------------
// K0: pre-fragment Wd (k'=2c+comp interleaved) and Wa/Wb (k=c planar) to bf16
// wfrag[i][ot(8)][m(4)][lane(64)][j(8)];  wab[i][mt(4)][ks(4)][lane(64)][j(8)]
// ---------------------------------------------------------------------------
__global__ __launch_bounds__(256) void k0_wfrag(
    const float* __restrict__ Wd, const float* __restrict__ Wa,
    const float* __restrict__ Wb, ushort_t* __restrict__ wfrag,
    ushort_t* __restrict__ wab)
{
  const int i = blockIdx.x;
  for (int e = threadIdx.x; e < 16384; e += 256) {
    int ot = e >> 11, m = (e >> 9) & 3, l = (e >> 3) & 63, j = e & 7;
    int r  = ot * 16 + (l & 15);
    // k-map: within m-step, k-row = gw*8 + j  <->  c = m*16 + gw*4 + (j>>1), comp = j&1
    int c = m * 16 + ((l >> 4) << 2) + (j >> 1), comp = j & 1;
    wfrag[(size_t)i * 16384 + e] = f2bf(Wd[(size_t)i * 16384 + r * 128 + comp * 64 + c]);
  }
  for (int e = threadIdx.x; e < 8192; e += 256) {
    int mt = e >> 11, ks = (e >> 9) & 3, l = (e >> 3) & 63, j = e & 7;
    int r  = mt * 16 + (l & 15);                 // 0..63: 0-31 Wa, 32-63 Wb
    int kp = ks * 32 + ((l >> 4) << 3) + j;      // channel 0..127
    float v = (r < 32) ? Wa[((size_t)i * 32 + r) * 128 + kp]
                       : Wb[((size_t)i * 32 + (r - 32)) * 128 + kp];
    wab[(size_t)i * 8192 + e] = f2bf(v);
  }
}

// ---------------------------------------------------------------------------
// K1: per (n, tc) with 4 t's: conv (MFMA, weights from wab) -> Ga/Gb
//     (k-layout half + t*16 + it, b64 writes) -> Gram via MFMA.
// Spart[3][32][64][25][25][2]
// ---------------------------------------------------------------------------
__global__ __launch_bounds__(256) void k1_spart(
    const float* __restrict__ xr, const float* __restrict__ xi,
    const ushort_t* __restrict__ wab, const float* __restrict__ ba,
    const float* __restrict__ bb, float* __restrict__ Spart)
{
  const int tc = blockIdx.x, n = blockIdx.y;
  const int tid = threadIdx.x, lane = tid & 63, wv = tid >> 6;
  const int r16 = lane & 15, gw = lane >> 4;
  __shared__ alignas(16) ushort_t zc[128 * 128]; // [pos2=t*32+v][c] swizzled
  __shared__ alignas(16) ushort_t Ga[32 * 128];  // [u][k: half + t*16 + it] swz
  __shared__ alignas(16) ushort_t Gb[32 * 128];

  // stage zc: float4 loads (100 contiguous floats per c = 25 float4)
  for (int e4 = tid; e4 < 128 * 25; e4 += 256) {
    int c = e4 / 25, q = e4 % 25;
    const float* src = (c < 64) ? xr : xi;
    float4 w = *(const float4*)&src[(size_t)n * CTV + (c & 63) * TV + tc * 100 + q * 4];
#pragma unroll
    for (int jj = 0; jj < 4; ++jj) {
      int g = q * 4 + jj, t = g / 25, v = g - t * 25;
      zc[SWZ(t * 32 + v, c)] = f2bf(((const float*)&w)[jj]);
    }
  }
  // zero-pad v=25..31
  for (int e = tid; e < 28 * 128; e += 256) {
    int r7 = e >> 7, c = e & 127;
    int t = r7 / 7, vv = 25 + r7 % 7;
    zc[SWZ(t * 32 + vv, c)] = 0;
  }

  const int mu = wv >> 1, nv = wv & 1;

  for (int i = 0; i < NS; ++i) {
    __syncthreads(); // zc ready (i==0); WAR on Ga/Gb vs previous gram

    // conv: wave wv = component (0=ar 1=ai 2=br 3=bi)
    {
      short8 afr[4];
#pragma unroll
      for (int ks = 0; ks < 4; ++ks)
        afr[ks] = *(const short8*)&wab[((((size_t)i * 4 + wv) * 4 + ks) * 64 + lane) * 8];
      float bias[4];
#pragma unroll
      for (int j = 0; j < 4; ++j) {
        int row = wv * 16 + gw * 4 + j;
        bias[j] = (row < 32) ? ba[i * 32 + row] : bb[i * 32 + (row - 32)];
      }
      ushort_t* gbuf = (wv < 2) ? Ga : Gb;
      const int half = (wv & 1) * 64;
      for (int nt = 0; nt < 8; ++nt) {
        f32x4 acc = {0.f, 0.f, 0.f, 0.f};
        const int brow = nt * 16 + r16;
#pragma unroll
        for (int ks = 0; ks < 4; ++ks) {
          short8 bfr = *(const short8*)&zc[SWZ(brow, ks * 32 + gw * 8)];
          acc = mfma16(afr[ks], bfr, acc);
        }
        int pos2 = nt * 16 + r16;
        int t = pos2 >> 5, v = pos2 & 31;
        int k0w = half + t * 16 + gw * 4;     // it = gw*4+j contiguous
        uint32_t w0 = (uint32_t)f2bf(acc[0] + bias[0]) | ((uint32_t)f2bf(acc[1] + bias[1]) << 16);
        uint32_t w1 = (uint32_t)f2bf(acc[2] + bias[2]) | ((uint32_t)f2bf(acc[3] + bias[3]) << 16);
        uint2 pk; pk.x = w0; pk.y = w1;
        *(uint2*)&gbuf[SWZ(v, k0w)] = pk;
      }
    }
    __syncthreads();

    // Gram via MFMA: wave (mu,nv) computes S[mu*16..+16)[nv*16..+16)
    {
      const int urow = mu * 16 + r16;
      const int vrow = nv * 16 + r16;
      f32x4 Prr = {0.f,0.f,0.f,0.f}, Pii = {0.f,0.f,0.f,0.f};
      f32x4 Pri = {0.f,0.f,0.f,0.f}, Pir = {0.f,0.f,0.f,0.f};
#pragma unroll
      for (int ks = 0; ks < 2; ++ks) {
        int ko = ks * 32 + gw * 8;
        short8 arF = *(const short8*)&Ga[SWZ(urow, ko)];
        short8 aiF = *(const short8*)&Ga[SWZ(urow, 64 + ko)];
        short8 brF = *(const short8*)&Gb[SWZ(vrow, ko)];
        short8 biF = *(const short8*)&Gb[SWZ(vrow, 64 + ko)];
        Prr = mfma16(arF, brF, Prr);
        Pii = mfma16(aiF, biF, Pii);
        Pri = mfma16(arF, biF, Pri);
        Pir = mfma16(aiF, brF, Pir);
      }
#pragma unroll
      for (int j = 0; j < 4; ++j) {
        int u = mu * 16 + gw * 4 + j;
        int v = nv * 16 + r16;
        if (u < VV && v < VV) {
          size_t idx = ((((size_t)i * NN + n) * 64 + tc) * 625 + u * 25 + v) * 2;
          Spart[idx]     = Prr[j] - Pii[j];
          Spart[idx + 1] = Pri[j] + Pir[j];
        }
      }
    }
  }
}

// ---------------------------------------------------------------------------
// K2: reduce Spart over tc, /4096, complex softmax over u, + (A+PA),
//     then emit packed bf16 hi/lo S-fragments in per-lane MFMA order.
// sfrag[i][n][m(4)][nt(2)][lane(64)][j(8)]  (m: Srh,Srl,Sih,Sil)
// ---------------------------------------------------------------------------
__global__ __launch_bounds__(256) void k2_softmax(
    const float* __restrict__ Spart, const float* __restrict__ Aw,
    const float* __restrict__ PA, ushort_t* __restrict__ sfrag)
{
  const int i = blockIdx.x, n = blockIdx.y, tid = threadIdx.x;
  __shared__ float ez[625 * 2];
  __shared__ float den[25 * 2];
  for (int e = tid; e < 625; e += 256) {
    float sr = 0.f, si = 0.f;
    const float* p = Spart + (((size_t)i * NN + n) * 64 * 625 + e) * 2;
    for (int tcb = 0; tcb < 64; ++tcb) { sr += p[0]; si += p[1]; p += 625 * 2; }
    sr *= (1.f / 4096.f); si *= (1.f / 4096.f);
    float m = expf(sr);
    ez[e * 2] = m * cosf(si);
    ez[e * 2 + 1] = m * sinf(si);
  }
  __syncthreads();
  if (tid < 25) {
    float dr = 0.f, di = 0.f;
    for (int u = 0; u < 25; ++u) { dr += ez[(u * 25 + tid) * 2]; di += ez[(u * 25 + tid) * 2 + 1]; }
    float inv = 1.f / (dr * dr + di * di);
    den[tid * 2] = dr * inv; den[tid * 2 + 1] = -di * inv; // conj(d)/|d|^2
  }
  __syncthreads();
  for (int e = tid; e < 625; e += 256) {
    int v = e % 25;
    float er = ez[e * 2], ei = ez[e * 2 + 1];
    float dr = den[v * 2], di = den[v * 2 + 1];
    float outr = er * dr - ei * di + Aw[i * 625 + e] + PA[i * 625 + e];
    float outi = er * di + ei * dr;
    ez[e * 2] = outr; ez[e * 2 + 1] = outi;   // finalize in place
  }
  __syncthreads();
  // pack fragments (m: 0=Srh 1=Srl 2=Sih 3=Sil)
  for (int e = tid; e < 512; e += 256) {
    int l = e & 63, nt = (e >> 6) & 1, m = e >> 7;
    int u0 = (l >> 4) << 3, v = nt * 16 + (l & 15);
    short8 pk;
#pragma unroll
    for (int j = 0; j < 8; ++j) {
      int u = u0 + j;
      float val = 0.f;
      if (u < VV && v < VV) {
        float sr_ = ez[(u * 25 + v) * 2], si_ = ez[(u * 25 + v) * 2 + 1];
        float base = (m < 2) ? sr_ : si_;
        if (m & 1) { float hi = bf2f(f2bf(base)); val = base - hi; }
        else val = base;
      }
      pk[j] = (short)f2bf(val);
    }
    *(short8*)&sfrag[((size_t)(i * NN + n) * 512 + e) * 8] = pk;
  }
}

// ---------------------------------------------------------------------------
// K3: block = (tq, n): 4 waves, wave wv owns t = tq*4+wv END-TO-END.
// z stays in registers (C-frag -> B-frag per-lane pack, k-perm baked in wfrag).
// Weights: bulk cooperative LDS stage per i (coalesced b128, one latency
// window), phase B reads conflict-free ds_read_b128. x hoisted to regs once;
// the wlds buffer reuses the xs LDS region.
// ---------------------------------------------------------------------------
__global__ __launch_bounds__(256) void k3_y(
    const float* __restrict__ xr, const float* __restrict__ xi,
    const ushort_t* __restrict__ sfrag, const ushort_t* __restrict__ wfrag,
    const float* __restrict__ bd, float* __restrict__ out,
    float* __restrict__ bnpart)
{
  const int tq = blockIdx.x, n = blockIdx.y;
  const int tid = threadIdx.x, lane = tid & 63, wv = tid >> 6;
  const int r16 = lane & 15, gw = lane >> 4;
  __shared__ alignas(16) ushort_t smem[16384]; // 32KB: xs (prologue) / wlds (loop)
  __shared__ float stats[4][128][2];

  // ---- prologue: cooperative x-stage into smem (xs layout, swizzled)
  for (int e4 = tid; e4 < 128 * 25; e4 += 256) {
    int c = e4 / 25, q = e4 % 25;
    const float* src = (c < 64) ? xr : xi;
    float4 w = *(const float4*)&src[(size_t)n * CTV + (c & 63) * TV + tq * 100 + q * 4];
#pragma unroll
    for (int jj = 0; jj < 4; ++jj) {
      int g = q * 4 + jj, t = g / 25, u = g - t * 25;
      smem[SWZ(c, t * 32 + u)] = f2bf(((const float*)&w)[jj]);
    }
  }
  for (int e = tid; e < 128 * 28; e += 256) { // pad u=25..31
    int c = e / 28, r = e % 28;
    int t = r / 7, u = 25 + r % 7;
    smem[SWZ(c, t * 32 + u)] = 0;
  }
  __syncthreads();

  // hoist x A-frags to registers (wave's t = tq*4 + wv)
  const int kx = wv * 32 + gw * 8;
  short8 axr[4], axi[4];
#pragma unroll
  for (int tile = 0; tile < 4; ++tile) {
    axr[tile] = *(const short8*)&smem[SWZ(tile * 16 + r16, kx)];
    axi[tile] = *(const short8*)&smem[SWZ(64 + tile * 16 + r16, kx)];
  }
  __syncthreads(); // xs dead; smem becomes wlds

  f32x4 acc[8][2];
#pragma unroll
  for (int a = 0; a < 8; ++a) { acc[a][0] = {0.f,0.f,0.f,0.f}; acc[a][1] = {0.f,0.f,0.f,0.f}; }

#pragma unroll 1
  for (int i = 0; i < NS; ++i) {
    // bulk stage wfrag[i] -> wlds: 8 coalesced b128 loads/thread (one window)
    {
      const ushort_t* wsrc = wfrag + (size_t)i * 16384;
      short8 tmp[8];
#pragma unroll
      for (int q = 0; q < 8; ++q)
        tmp[q] = *(const short8*)&wsrc[q * 2048 + tid * 8];
#pragma unroll
      for (int q = 0; q < 8; ++q)
        *(short8*)&smem[q * 2048 + tid * 8] = tmp[q];
    }
    // S fragments: 8 coalesced 16B loads (L2-hot); latency hides under barrier
    const ushort_t* sb = sfrag + (size_t)(i * NN + n) * 4096;
    short8 sf[4][2];
#pragma unroll
    for (int m = 0; m < 4; ++m)
#pragma unroll
      for (int nt = 0; nt < 2; ++nt)
        sf[m][nt] = *(const short8*)&sb[((m * 2 + nt) * 64 + lane) * 8];
    __syncthreads(); // wlds ready

    short8 sn0[2], sn1[2];
#pragma unroll
    for (int nt = 0; nt < 2; ++nt) { sn0[nt] = negbf8(sf[2][nt]); sn1[nt] = negbf8(sf[3][nt]); }

    // phase A: z = X2*S per c-tile; pack C-frag -> B-frag in registers
    short8 bp[4][2];
#pragma unroll
    for (int tile = 0; tile < 4; ++tile) {
#pragma unroll
      for (int nt = 0; nt < 2; ++nt) {
        f32x4 zr = {0.f,0.f,0.f,0.f}, zi = {0.f,0.f,0.f,0.f};
        zr = mfma16(axr[tile], sf[0][nt], zr);
        zr = mfma16(axr[tile], sf[1][nt], zr);
        zr = mfma16(axi[tile], sn0[nt], zr);
        zr = mfma16(axi[tile], sn1[nt], zr);
        zi = mfma16(axr[tile], sf[2][nt], zi);
        zi = mfma16(axr[tile], sf[3][nt], zi);
        zi = mfma16(axi[tile], sf[0][nt], zi);
        zi = mfma16(axi[tile], sf[1][nt], zi);
        short8 pk;
#pragma unroll
        for (int j = 0; j < 4; ++j) {
          pk[2 * j]     = (short)f2bf(zr[j]);
          pk[2 * j + 1] = (short)f2bf(zi[j]);
        }
        bp[tile][nt] = pk;
      }
    }

    // phase B: y += Wd[i] * z; a-frags via conflict-free ds_read_b128
#pragma unroll
    for (int ot = 0; ot < 8; ++ot) {
#pragma unroll
      for (int m = 0; m < 4; ++m) {
        short8 a = *(const short8*)&smem[(((ot * 4 + m) * 64) + lane) * 8];
        acc[ot][0] = mfma16(a, bp[m][0], acc[ot][0]);
        acc[ot][1] = mfma16(a, bp[m][1], acc[ot][1]);
      }
    }
    __syncthreads(); // WAR: next i's stage overwrites wlds
  }

  // epilogue: bias, write y (t = tq*4+wv), BN partials
  const int t = tq * 4 + wv;
#pragma unroll
  for (int ot = 0; ot < 8; ++ot) {
#pragma unroll
    for (int j = 0; j < 4; ++j) {
      int row = ot * 16 + gw * 4 + j;
      float bias = bd[row] + bd[128 + row] + bd[256 + row];
      float s = 0.f, q = 0.f;
#pragma unroll
      for (int nt = 0; nt < 2; ++nt) {
        int v = nt * 16 + r16;
        float val = acc[ot][nt][j] + bias;
        if (v < VV) {
          out[(size_t)(row >> 6) * PLANE + (size_t)n * CTV + (row & 63) * TV + t * VV + v] = val;
          s += val; q += val * val;
        }
      }
#pragma unroll
      for (int d = 1; d < 16; d <<= 1) { s += __shfl_xor(s, d); q += __shfl_xor(q, d); }
      if (r16 == 0) { stats[wv][row][0] = s; stats[wv][row][1] = q; }
    }
  }
  __syncthreads();
  if (tid < 128) {
    float s = stats[0][tid][0] + stats[1][tid][0] + stats[2][tid][0] + stats[3][tid][0];
    float q = stats[0][tid][1] + stats[1][tid][1] + stats[2][tid][1] + stats[3][tid][1];
    size_t b = (size_t)n * 64 + tq;
    bnpart[(b * 128 + tid) * 2]     = s;
    bnpart[(b * 128 + tid) * 2 + 1] = q;
  }
}

// ---------------------------------------------------------------------------
// K4: reduce bnpart (2048 partials) -> per-channel coeff
// ---------------------------------------------------------------------------
__global__ __launch_bounds__(256) void k4_stats(
    const float* __restrict__ bnpart, const float* __restrict__ bnw,
    const float* __restrict__ bnb, float* __restrict__ coeff)
{
  const int o = blockIdx.x, tid = threadIdx.x;
  float sr = 0.f, qr = 0.f, si = 0.f, qi = 0.f;
  for (int b = tid; b < 2048; b += 256) {
    const float* p = bnpart + ((size_t)b * 128 + o) * 2;
    sr += p[0]; qr += p[1];
    const float* p2 = bnpart + ((size_t)b * 128 + 64 + o) * 2;
    si += p2[0]; qi += p2[1];
  }
#pragma unroll
  for (int d = 1; d < 64; d <<= 1) {
    sr += __shfl_xor(sr, d); qr += __shfl_xor(qr, d);
    si += __shfl_xor(si, d); qi += __shfl_xor(qi, d);
  }
  __shared__ float red[4][4];
  int lane = tid & 63, wv = tid >> 6;
  if (lane == 0) { red[wv][0] = sr; red[wv][1] = qr; red[wv][2] = si; red[wv][3] = qi; }
  __syncthreads();
  if (tid == 0) {
    sr = red[0][0] + red[1][0] + red[2][0] + red[3][0];
    qr = red[0][1] + red[1][1] + red[2][1] + red[3][1];
    si = red[0][2] + red[1][2] + red[2][2] + red[3][2];
    qi = red[0][3] + red[1][3] + red[2][3] + red[3][3];
    const float invM = 1.f / (float)((size_t)NN * TTOT * VV);
    float mur = sr * invM, mui = si * invM;
    float var = (qr + qi) * invM - mur * mur - mui * mui;
    float inv = rsqrtf(var + 1e-5f);
    coeff[o * 4 + 0] = mur; coeff[o * 4 + 1] = mui;
    coeff[o * 4 + 2] = inv * bnw[o]; coeff[o * 4 + 3] = bnb[o];
  }
}

// ---------------------------------------------------------------------------
// K5: yn = (y - mu)*scale + shift + x  (in-place on d_out, vectorized)
// ---------------------------------------------------------------------------
__global__ __launch_bounds__(256) void k5_norm(
    const float* __restrict__ xr, const float* __restrict__ xi,
    const float* __restrict__ coeff, float* __restrict__ out)
{
  size_t idx0 = ((size_t)blockIdx.x * 256 + threadIdx.x) * 4;
  size_t stride = (size_t)gridDim.x * 256 * 4;
  for (size_t e = idx0; e < PLANE; e += stride) {
    int o = (int)((e / TV) & 63);
    float4 cf = *(const float4*)&coeff[o * 4];
    float4 yr = *(float4*)&out[e];
    float4 yi = *(float4*)&out[PLANE + e];
    float4 vr = *(const float4*)&xr[e];
    float4 vi = *(const float4*)&xi[e];
    yr.x = (yr.x - cf.x) * cf.z + cf.w + vr.x;
    yr.y = (yr.y - cf.x) * cf.z + cf.w + vr.y;
    yr.z = (yr.z - cf.x) * cf.z + cf.w + vr.z;
    yr.w = (yr.w - cf.x) * cf.z + cf.w + vr.w;
    yi.x = (yi.x - cf.y) * cf.z + vi.x;
    yi.y = (yi.y - cf.y) * cf.z + vi.y;
    yi.z = (yi.z - cf.y) * cf.z + vi.z;
    yi.w = (yi.w - cf.y) * cf.z + vi.w;
    *(float4*)&out[e] = yr;
    *(float4*)&out[PLANE + e] = yi;
  }
}

// ---------------------------------------------------------------------------
extern "C" void kernel_launch(void* const* d_in, const int* in_sizes, int n_in,
                              void* d_out, int out_size, void* d_ws, size_t ws_size,
                              hipStream_t stream) {
  const float* xr  = (const float*)d_in[0];
  const float* xi  = (const float*)d_in[1];
  const float* Aw  = (const float*)d_in[2];
  const float* PA  = (const float*)d_in[3];
  const float* Wa  = (const float*)d_in[4];
  const float* ba  = (const float*)d_in[5];
  const float* Wb  = (const float*)d_in[6];
  const float* bb  = (const float*)d_in[7];
  const float* Wd  = (const float*)d_in[8];
  const float* bd  = (const float*)d_in[9];
  const float* bnw = (const float*)d_in[10];
  const float* bnb = (const float*)d_in[11];
  float* out = (float*)d_out;
  float* ws = (float*)d_ws;

  // ws layout (floats). bnpart aliases Spart (Spart dead after k2).
  float*    Spart  = ws;                         // 7,680,000 floats
  float*    bnpart = ws;                         // 524,288 floats (alias)
  ushort_t* sfrag  = (ushort_t*)(ws + 7680000);  // 3*32*512*8 = 393,216 ushorts
  ushort_t* wfrag  = (ushort_t*)(ws + 7876608);  // 49,152 ushorts
  ushort_t* wab    = (ushort_t*)(ws + 7901184);  // 24,576 ushorts
  float*    coeff  = ws + 7913472;               // 256 floats
  // total ≈ 31.7 MB

  k0_wfrag<<<NS, 256, 0, stream>>>(Wd, Wa, Wb, wfrag, wab);
  k1_spart<<<dim3(64, NN), 256, 0, stream>>>(xr, xi, wab, ba, bb, Spart);
  k2_softmax<<<dim3(NS, NN), 256, 0, stream>>>(Spart, Aw, PA, sfrag);
  k3_y<<<dim3(64, NN), 256, 0, stream>>>(xr, xi, sfrag, wfrag, bd, out, bnpart);
  k4_stats<<<64, 256, 0, stream>>>(bnpart, bnw, bnb, coeff);
  k5_norm<<<6400, 256, 0, stream>>>(xr, xi, coeff, out);
}

// Round 9
// 245.189 us; speedup vs baseline: 1.2660x; 1.0049x over previous
//
#include <hip/hip_runtime.h>
#include <hip/hip_bf16.h>
#include <stdint.h>

#define NN 32
#define CC 64
#define TTOT 256
#define VV 25
#define NS 3
constexpr int TV  = TTOT * VV;            // 6400
constexpr int CTV = CC * TV;              // 409600
constexpr size_t PLANE = (size_t)NN * CTV; // 13107200

typedef unsigned short ushort_t;
using short8 = __attribute__((ext_vector_type(8))) short;
using f32x4  = __attribute__((ext_vector_type(4))) float;

static __device__ __forceinline__ ushort_t f2bf(float f) {
  __hip_bfloat16 h = __float2bfloat16(f);   // RNE, compiles to v_cvt
  return reinterpret_cast<ushort_t&>(h);
}
static __device__ __forceinline__ float bf2f(ushort_t h) {
  union { uint32_t u; float f; } v; v.u = ((uint32_t)h) << 16;
  return v.f;
}
// element offset into a [row][128] bf16 tile, XOR-swizzled (byte ^= (row&7)<<4)
static __device__ __forceinline__ int SWZ(int row, int k) {
  return ((row << 7) + k) ^ ((row & 7) << 3);
}
static __device__ __forceinline__ f32x4 mfma16(short8 a, short8 b, f32x4 c) {
  return __builtin_amdgcn_mfma_f32_16x16x32_bf16(a, b, c, 0, 0, 0);
}
static __device__ __forceinline__ short8 negbf8(short8 x) {
  short8 r;
#pragma unroll
  for (int j = 0; j < 8; ++j) r[j] = x[j] ^ (short)0x8000;
  return r;
}

// ---------------------------------------------------------------------------
// K0: pre-fragment Wd (k'=2c+comp interleaved) and Wa/Wb (k=c planar) to bf16
// wfrag[i][ot(8)][m(4)][lane(64)][j(8)];  wab[i][mt(4)][ks(4)][lane(64)][j(8)]
// ---------------------------------------------------------------------------
__global__ __launch_bounds__(256) void k0_wfrag(
    const float* __restrict__ Wd, const float* __restrict__ Wa,
    const float* __restrict__ Wb, ushort_t* __restrict__ wfrag,
    ushort_t* __restrict__ wab)
{
  const int i = blockIdx.x;
  for (int e = threadIdx.x; e < 16384; e += 256) {
    int ot = e >> 11, m = (e >> 9) & 3, l = (e >> 3) & 63, j = e & 7;
    int r  = ot * 16 + (l & 15);
    // k-map: within m-step, k-row = gw*8 + j  <->  c = m*16 + gw*4 + (j>>1), comp = j&1
    int c = m * 16 + ((l >> 4) << 2) + (j >> 1), comp = j & 1;
    wfrag[(size_t)i * 16384 + e] = f2bf(Wd[(size_t)i * 16384 + r * 128 + comp * 64 + c]);
  }
  for (int e = threadIdx.x; e < 8192; e += 256) {
    int mt = e >> 11, ks = (e >> 9) & 3, l = (e >> 3) & 63, j = e & 7;
    int r  = mt * 16 + (l & 15);                 // 0..63: 0-31 Wa, 32-63 Wb
    int kp = ks * 32 + ((l >> 4) << 3) + j;      // channel 0..127
    float v = (r < 32) ? Wa[((size_t)i * 32 + r) * 128 + kp]
                       : Wb[((size_t)i * 32 + (r - 32)) * 128 + kp];
    wab[(size_t)i * 8192 + e] = f2bf(v);
  }
}

// ---------------------------------------------------------------------------
// K1: per (n, tc) with 4 t's: conv (MFMA, weights from wab) -> Ga/Gb
//     (k-layout half + t*16 + it, b64 writes) -> Gram via MFMA.
// Spart[3][32][64][25][25][2]
// ---------------------------------------------------------------------------
__global__ __launch_bounds__(256) void k1_spart(
    const float* __restrict__ xr, const float* __restrict__ xi,
    const ushort_t* __restrict__ wab, const float* __restrict__ ba,
    const float* __restrict__ bb, float* __restrict__ Spart)
{
  const int tc = blockIdx.x, n = blockIdx.y;
  const int tid = threadIdx.x, lane = tid & 63, wv = tid >> 6;
  const int r16 = lane & 15, gw = lane >> 4;
  __shared__ alignas(16) ushort_t zc[128 * 128]; // [pos2=t*32+v][c] swizzled
  __shared__ alignas(16) ushort_t Ga[32 * 128];  // [u][k: half + t*16 + it] swz
  __shared__ alignas(16) ushort_t Gb[32 * 128];

  // stage zc: float4 loads (100 contiguous floats per c = 25 float4)
  for (int e4 = tid; e4 < 128 * 25; e4 += 256) {
    int c = e4 / 25, q = e4 % 25;
    const float* src = (c < 64) ? xr : xi;
    float4 w = *(const float4*)&src[(size_t)n * CTV + (c & 63) * TV + tc * 100 + q * 4];
#pragma unroll
    for (int jj = 0; jj < 4; ++jj) {
      int g = q * 4 + jj, t = g / 25, v = g - t * 25;
      zc[SWZ(t * 32 + v, c)] = f2bf(((const float*)&w)[jj]);
    }
  }
  // zero-pad v=25..31
  for (int e = tid; e < 28 * 128; e += 256) {
    int r7 = e >> 7, c = e & 127;
    int t = r7 / 7, vv = 25 + r7 % 7;
    zc[SWZ(t * 32 + vv, c)] = 0;
  }

  const int mu = wv >> 1, nv = wv & 1;

  for (int i = 0; i < NS; ++i) {
    __syncthreads(); // zc ready (i==0); WAR on Ga/Gb vs previous gram

    // conv: wave wv = component (0=ar 1=ai 2=br 3=bi)
    {
      short8 afr[4];
#pragma unroll
      for (int ks = 0; ks < 4; ++ks)
        afr[ks] = *(const short8*)&wab[((((size_t)i * 4 + wv) * 4 + ks) * 64 + lane) * 8];
      float bias[4];
#pragma unroll
      for (int j = 0; j < 4; ++j) {
        int row = wv * 16 + gw * 4 + j;
        bias[j] = (row < 32) ? ba[i * 32 + row] : bb[i * 32 + (row - 32)];
      }
      ushort_t* gbuf = (wv < 2) ? Ga : Gb;
      const int half = (wv & 1) * 64;
      for (int nt = 0; nt < 8; ++nt) {
        f32x4 acc = {0.f, 0.f, 0.f, 0.f};
        const int brow = nt * 16 + r16;
#pragma unroll
        for (int ks = 0; ks < 4; ++ks) {
          short8 bfr = *(const short8*)&zc[SWZ(brow, ks * 32 + gw * 8)];
          acc = mfma16(afr[ks], bfr, acc);
        }
        int pos2 = nt * 16 + r16;
        int t = pos2 >> 5, v = pos2 & 31;
        int k0w = half + t * 16 + gw * 4;     // it = gw*4+j contiguous
        uint32_t w0 = (uint32_t)f2bf(acc[0] + bias[0]) | ((uint32_t)f2bf(acc[1] + bias[1]) << 16);
        uint32_t w1 = (uint32_t)f2bf(acc[2] + bias[2]) | ((uint32_t)f2bf(acc[3] + bias[3]) << 16);
        uint2 pk; pk.x = w0; pk.y = w1;
        *(uint2*)&gbuf[SWZ(v, k0w)] = pk;
      }
    }
    __syncthreads();

    // Gram via MFMA: wave (mu,nv) computes S[mu*16..+16)[nv*16..+16)
    {
      const int urow = mu * 16 + r16;
      const int vrow = nv * 16 + r16;
      f32x4 Prr = {0.f,0.f,0.f,0.f}, Pii = {0.f,0.f,0.f,0.f};
      f32x4 Pri = {0.f,0.f,0.f,0.f}, Pir = {0.f,0.f,0.f,0.f};
#pragma unroll
      for (int ks = 0; ks < 2; ++ks) {
        int ko = ks * 32 + gw * 8;
        short8 arF = *(const short8*)&Ga[SWZ(urow, ko)];
        short8 aiF = *(const short8*)&Ga[SWZ(urow, 64 + ko)];
        short8 brF = *(const short8*)&Gb[SWZ(vrow, ko)];
        short8 biF = *(const short8*)&Gb[SWZ(vrow, 64 + ko)];
        Prr = mfma16(arF, brF, Prr);
        Pii = mfma16(aiF, biF, Pii);
        Pri = mfma16(arF, biF, Pri);
        Pir = mfma16(aiF, brF, Pir);
      }
#pragma unroll
      for (int j = 0; j < 4; ++j) {
        int u = mu * 16 + gw * 4 + j;
        int v = nv * 16 + r16;
        if (u < VV && v < VV) {
          size_t idx = ((((size_t)i * NN + n) * 64 + tc) * 625 + u * 25 + v) * 2;
          Spart[idx]     = Prr[j] - Pii[j];
          Spart[idx + 1] = Pri[j] + Pir[j];
        }
      }
    }
  }
}

// ---------------------------------------------------------------------------
// K2: reduce Spart over tc, /4096, complex softmax over u, + (A+PA),
//     then emit packed bf16 hi/lo S-fragments in per-lane MFMA order.
// sfrag[i][n][m(4)][nt(2)][lane(64)][j(8)]  (m: Srh,Srl,Sih,Sil)
// ---------------------------------------------------------------------------
__global__ __launch_bounds__(256) void k2_softmax(
    const float* __restrict__ Spart, const float* __restrict__ Aw,
    const float* __restrict__ PA, ushort_t* __restrict__ sfrag)
{
  const int i = blockIdx.x, n = blockIdx.y, tid = threadIdx.x;
  __shared__ float ez[625 * 2];
  __shared__ float den[25 * 2];
  for (int e = tid; e < 625; e += 256) {
    float sr = 0.f, si = 0.f;
    const float* p = Spart + (((size_t)i * NN + n) * 64 * 625 + e) * 2;
    for (int tcb = 0; tcb < 64; ++tcb) { sr += p[0]; si += p[1]; p += 625 * 2; }
    sr *= (1.f / 4096.f); si *= (1.f / 4096.f);
    float m = expf(sr);
    ez[e * 2] = m * cosf(si);
    ez[e * 2 + 1] = m * sinf(si);
  }
  __syncthreads();
  if (tid < 25) {
    float dr = 0.f, di = 0.f;
    for (int u = 0; u < 25; ++u) { dr += ez[(u * 25 + tid) * 2]; di += ez[(u * 25 + tid) * 2 + 1]; }
    float inv = 1.f / (dr * dr + di * di);
    den[tid * 2] = dr * inv; den[tid * 2 + 1] = -di * inv; // conj(d)/|d|^2
  }
  __syncthreads();
  for (int e = tid; e < 625; e += 256) {
    int v = e % 25;
    float er = ez[e * 2], ei = ez[e * 2 + 1];
    float dr = den[v * 2], di = den[v * 2 + 1];
    float outr = er * dr - ei * di + Aw[i * 625 + e] + PA[i * 625 + e];
    float outi = er * di + ei * dr;
    ez[e * 2] = outr; ez[e * 2 + 1] = outi;   // finalize in place
  }
  __syncthreads();
  // pack fragments (m: 0=Srh 1=Srl 2=Sih 3=Sil)
  for (int e = tid; e < 512; e += 256) {
    int l = e & 63, nt = (e >> 6) & 1, m = e >> 7;
    int u0 = (l >> 4) << 3, v = nt * 16 + (l & 15);
    short8 pk;
#pragma unroll
    for (int j = 0; j < 8; ++j) {
      int u = u0 + j;
      float val = 0.f;
      if (u < VV && v < VV) {
        float sr_ = ez[(u * 25 + v) * 2], si_ = ez[(u * 25 + v) * 2 + 1];
        float base = (m < 2) ? sr_ : si_;
        if (m & 1) { float hi = bf2f(f2bf(base)); val = base - hi; }
        else val = base;
      }
      pk[j] = (short)f2bf(val);
    }
    *(short8*)&sfrag[((size_t)(i * NN + n) * 512 + e) * 8] = pk;
  }
}

// ---------------------------------------------------------------------------
// K3: block = (tq, n): 512 threads / 8 waves; wave wv owns t = tq*8+wv.
// Prologue: stage x (64KB, coalesced) -> hoist x-frags to regs -> stage ALL
// THREE i's weights (96KB, reusing x region) -> one barrier. Then the whole
// 3-i loop is barrier-free: z stays in registers (C-frag -> B-frag pack),
// weights via conflict-free ds_read_b128, sfrag double-buffered.
// ---------------------------------------------------------------------------
__global__ __launch_bounds__(512, 2) void k3_y(
    const float* __restrict__ xr, const float* __restrict__ xi,
    const ushort_t* __restrict__ sfrag, const ushort_t* __restrict__ wfrag,
    const float* __restrict__ bd, float* __restrict__ out,
    float* __restrict__ bnpart)
{
  const int tq = blockIdx.x, n = blockIdx.y;
  const int tid = threadIdx.x, lane = tid & 63, wv = tid >> 6;
  const int r16 = lane & 15, gw = lane >> 4;
  __shared__ alignas(16) ushort_t wlds[49152]; // 96KB: xs (first 64KB) then weights
  __shared__ float stats[8][128][2];           // 8KB

  // ---- stage x for 8 t's into wlds[0..32768) as xs[2][128][128] (swizzled)
  {
    ushort_t* xs = wlds;
    for (int e4 = tid; e4 < 128 * 50; e4 += 512) {
      int c = e4 / 50, q = e4 % 50;
      const float* src = (c < 64) ? xr : xi;
      float4 w = *(const float4*)&src[(size_t)n * CTV + (c & 63) * TV + tq * 200 + q * 4];
#pragma unroll
      for (int jj = 0; jj < 4; ++jj) {
        int g = q * 4 + jj, t = g / 25, u = g - t * 25;
        xs[(t >> 2) * 16384 + SWZ(c, (t & 3) * 32 + u)] = f2bf(((const float*)&w)[jj]);
      }
    }
    for (int e = tid; e < 128 * 56; e += 512) { // pad u=25..31, all 8 t
      int c = e / 56, r = e % 56;
      int t = r / 7, u = 25 + r % 7;
      xs[(t >> 2) * 16384 + SWZ(c, (t & 3) * 32 + u)] = 0;
    }
  }
  __syncthreads();

  // hoist x A-frags (wave wv <-> local t = wv)
  const int tl = wv & 3, th = wv >> 2;
  const int kx = tl * 32 + gw * 8;
  short8 axr[4], axi[4];
#pragma unroll
  for (int tile = 0; tile < 4; ++tile) {
    axr[tile] = *(const short8*)&wlds[th * 16384 + SWZ(tile * 16 + r16, kx)];
    axi[tile] = *(const short8*)&wlds[th * 16384 + SWZ(64 + tile * 16 + r16, kx)];
  }
  __syncthreads(); // xs dead

  // stage ALL weights (3 i's, 96KB): 12 coalesced b128 per thread
  {
    short8 tmp[12];
#pragma unroll
    for (int q = 0; q < 12; ++q)
      tmp[q] = *(const short8*)&wfrag[(size_t)(q * 512 + tid) * 8];
#pragma unroll
    for (int q = 0; q < 12; ++q)
      *(short8*)&wlds[(size_t)(q * 512 + tid) * 8] = tmp[q];
  }
  __syncthreads(); // weights ready; loop below is barrier-free

  f32x4 acc[8][2];
#pragma unroll
  for (int a = 0; a < 8; ++a) { acc[a][0] = {0.f,0.f,0.f,0.f}; acc[a][1] = {0.f,0.f,0.f,0.f}; }

  auto load_sf = [&](int i, short8 sf[4][2]) {
    const ushort_t* sb = sfrag + (size_t)(i * NN + n) * 4096;
#pragma unroll
    for (int m = 0; m < 4; ++m)
#pragma unroll
      for (int nt = 0; nt < 2; ++nt)
        sf[m][nt] = *(const short8*)&sb[((m * 2 + nt) * 64 + lane) * 8];
  };
  auto compute_i = [&](int i, short8 sf[4][2]) {
    short8 sn0[2], sn1[2];
#pragma unroll
    for (int nt = 0; nt < 2; ++nt) { sn0[nt] = negbf8(sf[2][nt]); sn1[nt] = negbf8(sf[3][nt]); }
    short8 bp[4][2];
#pragma unroll
    for (int tile = 0; tile < 4; ++tile) {
#pragma unroll
      for (int nt = 0; nt < 2; ++nt) {
        f32x4 zr = {0.f,0.f,0.f,0.f}, zi = {0.f,0.f,0.f,0.f};
        zr = mfma16(axr[tile], sf[0][nt], zr);
        zr = mfma16(axr[tile], sf[1][nt], zr);
        zr = mfma16(axi[tile], sn0[nt], zr);
        zr = mfma16(axi[tile], sn1[nt], zr);
        zi = mfma16(axr[tile], sf[2][nt], zi);
        zi = mfma16(axr[tile], sf[3][nt], zi);
        zi = mfma16(axi[tile], sf[0][nt], zi);
        zi = mfma16(axi[tile], sf[1][nt], zi);
        short8 pk;
#pragma unroll
        for (int j = 0; j < 4; ++j) {
          pk[2 * j]     = (short)f2bf(zr[j]);
          pk[2 * j + 1] = (short)f2bf(zi[j]);
        }
        bp[tile][nt] = pk;
      }
    }
#pragma unroll
    for (int ot = 0; ot < 8; ++ot) {
#pragma unroll
      for (int m = 0; m < 4; ++m) {
        short8 a = *(const short8*)&wlds[((size_t)i * 16384) + (size_t)((ot * 4 + m) * 64 + lane) * 8];
        acc[ot][0] = mfma16(a, bp[m][0], acc[ot][0]);
        acc[ot][1] = mfma16(a, bp[m][1], acc[ot][1]);
      }
    }
  };

  // software-pipelined sfrag: prefetch next i during compute of current
  short8 sfA[4][2], sfB[4][2];
  load_sf(0, sfA);
  load_sf(1, sfB);
  compute_i(0, sfA);
  load_sf(2, sfA);
  compute_i(1, sfB);
  compute_i(2, sfA);

  // epilogue: bias, write y (t = tq*8+wv), BN partials
  const int t = tq * 8 + wv;
#pragma unroll
  for (int ot = 0; ot < 8; ++ot) {
#pragma unroll
    for (int j = 0; j < 4; ++j) {
      int row = ot * 16 + gw * 4 + j;
      float bias = bd[row] + bd[128 + row] + bd[256 + row];
      float s = 0.f, q = 0.f;
#pragma unroll
      for (int nt = 0; nt < 2; ++nt) {
        int v = nt * 16 + r16;
        float val = acc[ot][nt][j] + bias;
        if (v < VV) {
          out[(size_t)(row >> 6) * PLANE + (size_t)n * CTV + (row & 63) * TV + t * VV + v] = val;
          s += val; q += val * val;
        }
      }
#pragma unroll
      for (int d = 1; d < 16; d <<= 1) { s += __shfl_xor(s, d); q += __shfl_xor(q, d); }
      if (r16 == 0) { stats[wv][row][0] = s; stats[wv][row][1] = q; }
    }
  }
  __syncthreads();
  if (tid < 128) {
    float s = 0.f, q = 0.f;
#pragma unroll
    for (int w = 0; w < 8; ++w) { s += stats[w][tid][0]; q += stats[w][tid][1]; }
    size_t b = (size_t)n * 32 + tq;
    bnpart[(b * 128 + tid) * 2]     = s;
    bnpart[(b * 128 + tid) * 2 + 1] = q;
  }
}

// ---------------------------------------------------------------------------
// K4: reduce bnpart (1024 partials) -> per-channel coeff
// ---------------------------------------------------------------------------
__global__ __launch_bounds__(256) void k4_stats(
    const float* __restrict__ bnpart, const float* __restrict__ bnw,
    const float* __restrict__ bnb, float* __restrict__ coeff)
{
  const int o = blockIdx.x, tid = threadIdx.x;
  float sr = 0.f, qr = 0.f, si = 0.f, qi = 0.f;
  for (int b = tid; b < 1024; b += 256) {
    const float* p = bnpart + ((size_t)b * 128 + o) * 2;
    sr += p[0]; qr += p[1];
    const float* p2 = bnpart + ((size_t)b * 128 + 64 + o) * 2;
    si += p2[0]; qi += p2[1];
  }
#pragma unroll
  for (int d = 1; d < 64; d <<= 1) {
    sr += __shfl_xor(sr, d); qr += __shfl_xor(qr, d);
    si += __shfl_xor(si, d); qi += __shfl_xor(qi, d);
  }
  __shared__ float red[4][4];
  int lane = tid & 63, wv = tid >> 6;
  if (lane == 0) { red[wv][0] = sr; red[wv][1] = qr; red[wv][2] = si; red[wv][3] = qi; }
  __syncthreads();
  if (tid == 0) {
    sr = red[0][0] + red[1][0] + red[2][0] + red[3][0];
    qr = red[0][1] + red[1][1] + red[2][1] + red[3][1];
    si = red[0][2] + red[1][2] + red[2][2] + red[3][2];
    qi = red[0][3] + red[1][3] + red[2][3] + red[3][3];
    const float invM = 1.f / (float)((size_t)NN * TTOT * VV);
    float mur = sr * invM, mui = si * invM;
    float var = (qr + qi) * invM - mur * mur - mui * mui;
    float inv = rsqrtf(var + 1e-5f);
    coeff[o * 4 + 0] = mur; coeff[o * 4 + 1] = mui;
    coeff[o * 4 + 2] = inv * bnw[o]; coeff[o * 4 + 3] = bnb[o];
  }
}

// ---------------------------------------------------------------------------
// K5: yn = (y - mu)*scale + shift + x  (in-place on d_out, vectorized)
// ---------------------------------------------------------------------------
__global__ __launch_bounds__(256) void k5_norm(
    const float* __restrict__ xr, const float* __restrict__ xi,
    const float* __restrict__ coeff, float* __restrict__ out)
{
  size_t idx0 = ((size_t)blockIdx.x * 256 + threadIdx.x) * 4;
  size_t stride = (size_t)gridDim.x * 256 * 4;
  for (size_t e = idx0; e < PLANE; e += stride) {
    int o = (int)((e / TV) & 63);
    float4 cf = *(const float4*)&coeff[o * 4];
    float4 yr = *(float4*)&out[e];
    float4 yi = *(float4*)&out[PLANE + e];
    float4 vr = *(const float4*)&xr[e];
    float4 vi = *(const float4*)&xi[e];
    yr.x = (yr.x - cf.x) * cf.z + cf.w + vr.x;
    yr.y = (yr.y - cf.x) * cf.z + cf.w + vr.y;
    yr.z = (yr.z - cf.x) * cf.z + cf.w + vr.z;
    yr.w = (yr.w - cf.x) * cf.z + cf.w + vr.w;
    yi.x = (yi.x - cf.y) * cf.z + vi.x;
    yi.y = (yi.y - cf.y) * cf.z + vi.y;
    yi.z = (yi.z - cf.y) * cf.z + vi.z;
    yi.w = (yi.w - cf.y) * cf.z + vi.w;
    *(float4*)&out[e] = yr;
    *(float4*)&out[PLANE + e] = yi;
  }
}

// ---------------------------------------------------------------------------
extern "C" void kernel_launch(void* const* d_in, const int* in_sizes, int n_in,
                              void* d_out, int out_size, void* d_ws, size_t ws_size,
                              hipStream_t stream) {
  const float* xr  = (const float*)d_in[0];
  const float* xi  = (const float*)d_in[1];
  const float* Aw  = (const float*)d_in[2];
  const float* PA  = (const float*)d_in[3];
  const float* Wa  = (const float*)d_in[4];
  const float* ba  = (const float*)d_in[5];
  const float* Wb  = (const float*)d_in[6];
  const float* bb  = (const float*)d_in[7];
  const float* Wd  = (const float*)d_in[8];
  const float* bd  = (const float*)d_in[9];
  const float* bnw = (const float*)d_in[10];
  const float* bnb = (const float*)d_in[11];
  float* out = (float*)d_out;
  float* ws = (float*)d_ws;

  // ws layout (floats). bnpart aliases Spart (Spart dead after k2).
  float*    Spart  = ws;                         // 7,680,000 floats
  float*    bnpart = ws;                         // 262,144 floats (alias)
  ushort_t* sfrag  = (ushort_t*)(ws + 7680000);  // 3*32*512*8 = 393,216 ushorts
  ushort_t* wfrag  = (ushort_t*)(ws + 7876608);  // 49,152 ushorts
  ushort_t* wab    = (ushort_t*)(ws + 7901184);  // 24,576 ushorts
  float*    coeff  = ws + 7913472;               // 256 floats
  // total ≈ 31.7 MB

  k0_wfrag<<<NS, 256, 0, stream>>>(Wd, Wa, Wb, wfrag, wab);
  k1_spart<<<dim3(64, NN), 256, 0, stream>>>(xr, xi, wab, ba, bb, Spart);
  k2_softmax<<<dim3(NS, NN), 256, 0, stream>>>(Spart, Aw, PA, sfrag);
  k3_y<<<dim3(32, NN), 512, 0, stream>>>(xr, xi, sfrag, wfrag, bd, out, bnpart);
  k4_stats<<<64, 256, 0, stream>>>(bnpart, bnw, bnb, coeff);
  k5_norm<<<6400, 256, 0, stream>>>(xr, xi, coeff, out);
}